// Round 1
// baseline (354.533 us; speedup 1.0000x reference)
//
#include <hip/hip_runtime.h>

// BacklashNet: per-row nonlinear scan.
//   lo = fl(fl(m_lo*x) + fl(m_lo*c_lo)), up analogous.
//   f1 = (lo <= prev), f2 = (fl(prev - fl(m_up*x)) <= fl(m_up*c_up))
//   out = f1 ? (f2 ? fl(fl(lo + A2) + muc) : lo) : (f2 ? up : prev)
// All roundings replicate the numpy/JAX fp32 reference exactly (no FMA
// contraction, same operation order) because branch flips at the f1&f2
// boundary amplify 1-ulp state differences into O(1) output errors.

namespace {

constexpr int kB  = 2048;
constexpr int kT  = 8192;
constexpr int kPF = 8;  // prefetch depth in 8-step chunks (64 steps ~ 1600 cyc ahead)

__device__ __forceinline__ float bstep(float xv, float prev, float m_lo, float m_up,
                                       float mlc, float muc) {
  // off-chain (depends on xv only):
  float A1 = __fmul_rn(m_lo, xv);
  float B1 = __fadd_rn(A1, mlc);            // "lo"
  float A2 = __fmul_rn(m_up, xv);
  float B2 = __fadd_rn(A2, muc);            // "up"
  float C  = __fadd_rn(__fadd_rn(B1, A2), muc);  // f1&f2 case, exact ref ordering
  // dependent chain (4 levels): sub -> cmp -> sel -> sel
  float u  = __fsub_rn(prev, A2);
  bool  f1 = (B1 <= prev);                  // sign-exact reduction of s1 <= 0
  bool  f2 = (u <= muc);                    // sign-exact reduction of s2 <= 0
  float hi = f2 ? C  : B1;
  float lo = f2 ? B2 : prev;
  return f1 ? hi : lo;
}

__global__ __launch_bounds__(64, 1) void backlash_kernel(
    const float* __restrict__ x, const float* __restrict__ p0,
    const float* __restrict__ w, float* __restrict__ out) {
  const int r = blockIdx.x * 64 + threadIdx.x;  // one thread per row, r < 2048

  const float m_lo = w[0], m_up = w[1], c_lo = w[2], c_up = w[3];
  const float mlc = __fmul_rn(m_lo, c_lo);
  const float muc = __fmul_rn(m_up, c_up);

  float prev = p0[r];

  const float4* __restrict__ xr   = reinterpret_cast<const float4*>(x + (size_t)r * kT);
  float4* __restrict__       orow = reinterpret_cast<float4*>(out + (size_t)r * kT);

  constexpr int NC = kT / 8;  // 1024 chunks of 8 timesteps
  float4 buf[2 * kPF];        // rolling register prefetch window

#pragma unroll
  for (int j = 0; j < kPF; ++j) {
    buf[2 * j]     = xr[2 * j];
    buf[2 * j + 1] = xr[2 * j + 1];
  }

#pragma unroll 8
  for (int i = 0; i < NC; ++i) {
    const int s = i & (kPF - 1);   // static after unroll-by-8
    float4 a = buf[2 * s];
    float4 b = buf[2 * s + 1];
    if (i + kPF < NC) {
      buf[2 * s]     = xr[2 * (i + kPF)];
      buf[2 * s + 1] = xr[2 * (i + kPF) + 1];
    }
    float4 o1, o2;
    prev = bstep(a.x, prev, m_lo, m_up, mlc, muc); o1.x = prev;
    prev = bstep(a.y, prev, m_lo, m_up, mlc, muc); o1.y = prev;
    prev = bstep(a.z, prev, m_lo, m_up, mlc, muc); o1.z = prev;
    prev = bstep(a.w, prev, m_lo, m_up, mlc, muc); o1.w = prev;
    prev = bstep(b.x, prev, m_lo, m_up, mlc, muc); o2.x = prev;
    prev = bstep(b.y, prev, m_lo, m_up, mlc, muc); o2.y = prev;
    prev = bstep(b.z, prev, m_lo, m_up, mlc, muc); o2.z = prev;
    prev = bstep(b.w, prev, m_lo, m_up, mlc, muc); o2.w = prev;
    orow[2 * i]     = o1;
    orow[2 * i + 1] = o2;
  }
}

}  // namespace

extern "C" void kernel_launch(void* const* d_in, const int* in_sizes, int n_in,
                              void* d_out, int out_size, void* d_ws, size_t ws_size,
                              hipStream_t stream) {
  const float* x  = (const float*)d_in[0];   // (B, T, 1) fp32
  const float* p0 = (const float*)d_in[1];   // (B, 1, 1) fp32
  const float* w  = (const float*)d_in[2];   // (4,) fp32
  float* out = (float*)d_out;                // (B, T, 1) fp32
  (void)in_sizes; (void)n_in; (void)out_size; (void)d_ws; (void)ws_size;
  backlash_kernel<<<kB / 64, 64, 0, stream>>>(x, p0, w, out);
}